// Round 7
// baseline (1834.595 us; speedup 1.0000x reference)
//
#include <hip/hip_runtime.h>

#define B 8
#define N 20000
#define M 256
#define I 64
#define O 64
#define MI (M * I)          // 16384
#define ROWS 16             // x-chunk rows per LDS buffer
#define IH 32               // i-columns per block (i-split of 2)

// ---------------- Stage 1: partial tiles of dtx[b][m][i] = sum_n D[b,n,m]*x[b,n,i]
// Block = (s, b, ih): 256m x 32i tile, K = chunk rows. Thread owns 4m x 8i = 32
// accumulators (the 64-acc tile needed ~135 VGPR -> stuck on the wrong side of
// the 128-VGPR/4-wave cliff in r4/r5/r6). D read straight from global
// (coalesced dwordx4, one consumer lane). x (32 floats/row) double-buffered in
// 4 KB LDS, broadcast reads. Cap 128 VGPR / 4 blocks/CU; demand ~90 -> no spill.
__global__ __launch_bounds__(256, 4) void stage1(const float* __restrict__ Dg,
                                                 const float* __restrict__ xg,
                                                 float* __restrict__ partial,
                                                 int chunk) {
    const int b  = blockIdx.y;
    const int s  = blockIdx.x;
    const int ih = blockIdx.z;            // 0/1: which 32-wide i half
    const int n0 = s * chunk;
    const int nend = min(n0 + chunk, N);
    const int tid = threadIdx.x;
    const int m_base = (tid & 63) * 4;
    const int iq = tid >> 6;              // 0..3
    const int i_loc = iq * 8;             // i offset within the 32-wide half

    __shared__ float ldsX[2][ROWS][IH];   // 4 KB

    float acc[4][8];
#pragma unroll
    for (int a = 0; a < 4; ++a)
#pragma unroll
        for (int cc = 0; cc < 8; ++cc) acc[a][cc] = 0.f;

    const float* Dbase = Dg + (size_t)b * N * M + m_base;       // per-lane col base
    const float* xbase = xg + (size_t)b * N * I + ih * IH;

    const int xr = tid >> 4;          // 0..15 (x staging row)
    const int xc = (tid & 15) * 2;    // 0..30 (x staging col, float2)

    const int steps = (nend > n0) ? (nend - n0 + ROWS - 1) / ROWS : 0;
    const float4 z4 = make_float4(0.f, 0.f, 0.f, 0.f);

    if (steps > 0) {
        // stage x chunk 0 (clamped row safe: matching D rows are zeroed)
        {
            const int nr = min(n0 + xr, N - 1);
            *(float2*)&ldsX[0][xr][xc] = *(const float2*)&xbase[(size_t)nr * I + xc];
        }
        // prefetch D rows 0..3 into registers
        float4 dc[4];
#pragma unroll
        for (int k = 0; k < 4; ++k) {
            const int n1 = n0 + k;
            dc[k] = (n1 < nend) ? *(const float4*)&Dbase[(size_t)n1 * M] : z4;
        }
        __syncthreads();   // x chunk 0 visible

        for (int t = 0; t < steps; ++t) {
            const int cur = t & 1;
            const int base = n0 + t * ROWS;
            const bool morex = (t + 1 < steps);
            float2 xstage = make_float2(0.f, 0.f);
            if (morex) {   // issue next x chunk's load early (hides under compute)
                const int nr = min(base + ROWS + xr, N - 1);
                xstage = *(const float2*)&xbase[(size_t)nr * I + xc];
            }
#pragma unroll
            for (int g = 0; g < ROWS / 4; ++g) {
                // prefetch next 4 D rows (crosses into next chunk at g=3)
                float4 dn[4];
#pragma unroll
                for (int k = 0; k < 4; ++k) {
                    const int n1 = base + (g + 1) * 4 + k;
                    dn[k] = (n1 < nend) ? *(const float4*)&Dbase[(size_t)n1 * M] : z4;
                }
                // compute rows g*4 .. g*4+3 with previously-loaded D
#pragma unroll
                for (int k = 0; k < 4; ++k) {
                    const int r = g * 4 + k;
                    const float4 d4 = dc[k];
                    float xv[8];
                    *(float4*)&xv[0] = *(const float4*)&ldsX[cur][r][i_loc + 0];
                    *(float4*)&xv[4] = *(const float4*)&ldsX[cur][r][i_loc + 4];
                    const float dm[4] = {d4.x, d4.y, d4.z, d4.w};
#pragma unroll
                    for (int a = 0; a < 4; ++a)
#pragma unroll
                        for (int cc = 0; cc < 8; ++cc)
                            acc[a][cc] = fmaf(dm[a], xv[cc], acc[a][cc]);
                }
#pragma unroll
                for (int k = 0; k < 4; ++k) dc[k] = dn[k];
            }
            __syncthreads();               // all reads of ldsX[cur] done
            if (morex)
                *(float2*)&ldsX[cur ^ 1][xr][xc] = xstage;
            __syncthreads();               // next buffer visible
        }
    }

    // store partial tile, coalesced: j = ih*8192 + (a*8+cc)*256 + tid
    float* p = partial + ((size_t)s * B + b) * MI + ih * (M * IH);
#pragma unroll
    for (int a = 0; a < 4; ++a)
#pragma unroll
        for (int cc = 0; cc < 8; ++cc)
            p[((a * 8 + cc) << 8) + tid] = acc[a][cc];
}

// ---------------- Reduce: dtx[b][m][i] = sum_s partial[s][b][j(m,i)]
__global__ __launch_bounds__(256) void reduce_partials(const float* __restrict__ partial,
                                                       float* __restrict__ dtx,
                                                       int nsplit) {
    const int bb = blockIdx.y;
    const int j = blockIdx.x * 256 + threadIdx.x;   // 0..MI-1
    const float* p = partial + (size_t)bb * MI + j;
    float sum = 0.f;
#pragma unroll 4
    for (int s = 0; s < nsplit; ++s)
        sum += p[(size_t)s * B * MI];
    // invert stage1 layout: j = ih*8192 + cidx*256 + t
    const int ihh  = j >> 13;
    const int jj   = j & 8191;
    const int cidx = jj >> 8;     // 0..31 = a*8+cc
    const int t    = jj & 255;
    const int m = (t & 63) * 4 + (cidx >> 3);
    const int i = ihh * IH + (t >> 6) * 8 + (cidx & 7);
    dtx[(size_t)bb * MI + m * I + i] = sum;
}

// ---------------- Stage 2: S[b][m][o] = (1/16) * sum_i coeff[o][i][m] * dtx[b][m][i]
__global__ __launch_bounds__(256) void stage2(const float* __restrict__ coeff,
                                              const float* __restrict__ dtx,
                                              float* __restrict__ S) {
    const int g = blockIdx.x * 256 + threadIdx.x;   // 0 .. B*O*M-1
    const int b = g >> 14;            // O*M = 16384
    const int rem = g & 16383;
    const int o = rem >> 8;
    const int m = rem & 255;
    const float* dt = dtx + (size_t)b * M * I + (size_t)m * I;
    const float* cf = coeff + (size_t)o * I * M + m;
    float acc = 0.f;
#pragma unroll 8
    for (int i = 0; i < I; ++i)
        acc = fmaf(cf[(size_t)i * M], dt[i], acc);
    S[(size_t)b * M * O + (size_t)m * O + o] = acc * 0.0625f;   // 1/sqrt(256)
}

// ---------------- Stage 3: out[b][n][o] = sum_m D[b][n][m] * S[b][m][o]
// NTILE=256, thread owns 4 n x 16 o (64 acc) -> 64 FMA per m-step.
#define MC 32
#define NT3 256
#define NBLK3 ((N + NT3 - 1) / NT3)   // 79

__global__ __launch_bounds__(256) void stage3(const float* __restrict__ Dg,
                                              const float* __restrict__ Sg,
                                              float* __restrict__ outg) {
    const int b = blockIdx.y;
    const int n0 = blockIdx.x * NT3;
    const int tid = threadIdx.x;
    const int nl = tid & 63;
    const int o_base = (tid >> 6) * 16;

    __shared__ float Dt[NT3][MC + 1];   // 33 KB, stride 33 -> 2-way max (free)
    __shared__ float St[MC][O];         // 8 KB

    float acc[4][16];
#pragma unroll
    for (int w = 0; w < 4; ++w)
#pragma unroll
        for (int j = 0; j < 16; ++j) acc[w][j] = 0.f;

    const float* Db = Dg + (size_t)b * N * M;
    const float* Sb = Sg + (size_t)b * M * O;

    for (int mc = 0; mc < M; mc += MC) {
#pragma unroll
        for (int rr = 0; rr < 8; ++rr) {
            const int f = tid + rr * 256;      // 0..2047 float4 slots
            const int n_row = f >> 3;          // 0..255
            const int m_off = (f & 7) * 4;     // 0..28
            const int gn = min(n0 + n_row, N - 1);
            float4 d4 = *(const float4*)&Db[(size_t)gn * M + mc + m_off];
            Dt[n_row][m_off + 0] = d4.x;
            Dt[n_row][m_off + 1] = d4.y;
            Dt[n_row][m_off + 2] = d4.z;
            Dt[n_row][m_off + 3] = d4.w;
            if (rr < 2) {   // S chunk: contiguous copy of 2048 floats
                *(float4*)((float*)St + (size_t)f * 4) =
                    *(const float4*)&Sb[(size_t)mc * O + (size_t)f * 4];
            }
        }
        __syncthreads();
#pragma unroll 4
        for (int mm = 0; mm < MC; ++mm) {
            float dv[4];
#pragma unroll
            for (int w = 0; w < 4; ++w) dv[w] = Dt[nl + 64 * w][mm];
            float sv[16];
            *(float4*)&sv[0]  = *(const float4*)&St[mm][o_base + 0];
            *(float4*)&sv[4]  = *(const float4*)&St[mm][o_base + 4];
            *(float4*)&sv[8]  = *(const float4*)&St[mm][o_base + 8];
            *(float4*)&sv[12] = *(const float4*)&St[mm][o_base + 12];
#pragma unroll
            for (int w = 0; w < 4; ++w)
#pragma unroll
                for (int j = 0; j < 16; ++j)
                    acc[w][j] = fmaf(dv[w], sv[j], acc[w][j]);
        }
        __syncthreads();
    }

#pragma unroll
    for (int w = 0; w < 4; ++w) {
        const int gn = n0 + nl + 64 * w;
        if (gn < N) {
            float* op = outg + ((size_t)b * N + gn) * O + o_base;
            *(float4*)&op[0]  = make_float4(acc[w][0],  acc[w][1],  acc[w][2],  acc[w][3]);
            *(float4*)&op[4]  = make_float4(acc[w][4],  acc[w][5],  acc[w][6],  acc[w][7]);
            *(float4*)&op[8]  = make_float4(acc[w][8],  acc[w][9],  acc[w][10], acc[w][11]);
            *(float4*)&op[12] = make_float4(acc[w][12], acc[w][13], acc[w][14], acc[w][15]);
        }
    }
}

extern "C" void kernel_launch(void* const* d_in, const int* in_sizes, int n_in,
                              void* d_out, int out_size, void* d_ws, size_t ws_size,
                              hipStream_t stream) {
    const float* Dg    = (const float*)d_in[0];
    const float* xg    = (const float*)d_in[1];
    const float* coeff = (const float*)d_in[2];
    float* outg = (float*)d_out;

    float* dtx     = (float*)d_ws;                   // B*MI floats = 512 KB
    float* S       = dtx + (size_t)B * MI;           // B*M*O floats = 512 KB
    float* partial = S + (size_t)B * M * O;          // split * B*MI floats

    // Choose split-K factor from available workspace (deterministic in ws_size).
    // Cap 64: grid 64*8*2 = 1024 blocks = one full residency pass at 4 blocks/CU.
    const size_t fixed = 2ull * B * MI * sizeof(float);
    const size_t per   = (size_t)B * MI * sizeof(float);   // 512 KB per slot
    int split = 1;
    if (ws_size > fixed) {
        size_t cap = (ws_size - fixed) / per;
        split = (int)(cap < 1 ? 1 : (cap > 64 ? 64 : cap));
    }
    int chunk = ((N + split - 1) / split + ROWS - 1) & ~(ROWS - 1);

    stage1<<<dim3(split, B, 2), 256, 0, stream>>>(Dg, xg, partial, chunk);
    reduce_partials<<<dim3(MI / 256, B), 256, 0, stream>>>(partial, dtx, split);
    stage2<<<dim3((B * O * M) / 256), 256, 0, stream>>>(coeff, dtx, S);
    stage3<<<dim3(NBLK3, B), 256, 0, stream>>>(Dg, S, outg);
}

// Round 8
// 272.523 us; speedup vs baseline: 6.7319x; 6.7319x over previous
//
#include <hip/hip_runtime.h>

#define B 8
#define N 20000
#define M 256
#define I 64
#define O 64
#define MI (M * I)          // 16384
#define ROWS 16             // x-chunk rows per LDS buffer
#define MH 128              // m-columns per block (m-split of 2)

// ---------------- Stage 1: partial tiles of dtx[b][m][i] = sum_n D[b,n,m]*x[b,n,i]
// Block = (s, b, mh): 128m x 64i tile. Thread owns 2m x 16i = 32 accumulators.
// DEMAND-BASED OCCUPANCY: no min-waves clause (r5/r7 proved `(256,4)` maps to
// waves-per-eu and forces a 64-VGPR spill regardless of demand). 32-acc tile
// keeps true demand ~80 VGPR -> allocator lands ~96-112 -> 4-5 waves/SIMD.
// D read straight from global (float2/lane, wave = 512 contiguous B, one
// consumer); x (64 floats/row) double-buffered in 8 KB LDS, broadcast reads.
// m-split duplicates only x traffic (41 MB), not D (164 MB).
__global__ __launch_bounds__(256) void stage1(const float* __restrict__ Dg,
                                              const float* __restrict__ xg,
                                              float* __restrict__ partial,
                                              int chunk) {
    const int b  = blockIdx.y;
    const int s  = blockIdx.x;
    const int mh = blockIdx.z;            // 0/1: which 128-wide m half
    const int n0 = s * chunk;
    const int nend = min(n0 + chunk, N);
    const int tid = threadIdx.x;
    const int m_base = mh * MH + (tid & 63) * 2;   // lane-contiguous float2
    const int i_base = (tid >> 6) * 16;

    __shared__ float ldsX[2][ROWS][I];    // 8 KB

    float acc[2][16];
#pragma unroll
    for (int a = 0; a < 2; ++a)
#pragma unroll
        for (int cc = 0; cc < 16; ++cc) acc[a][cc] = 0.f;

    const float* Dbase = Dg + (size_t)b * N * M + m_base;   // per-lane col base
    const float* xbase = xg + (size_t)b * N * I;

    const int xr = tid >> 4;          // 0..15 (x staging row)
    const int xc = (tid & 15) * 4;    // 0..60 (x staging col, float4)

    const int steps = (nend > n0) ? (nend - n0 + ROWS - 1) / ROWS : 0;
    const float2 z2 = make_float2(0.f, 0.f);

    if (steps > 0) {
        // stage x chunk 0 (clamped row safe: matching D rows are zeroed)
        {
            const int nr = min(n0 + xr, N - 1);
            *(float4*)&ldsX[0][xr][xc] = *(const float4*)&xbase[(size_t)nr * I + xc];
        }
        // prefetch D rows 0..3 into registers
        float2 dc[4];
#pragma unroll
        for (int k = 0; k < 4; ++k) {
            const int n1 = n0 + k;
            dc[k] = (n1 < nend) ? *(const float2*)&Dbase[(size_t)n1 * M] : z2;
        }
        __syncthreads();   // x chunk 0 visible

        for (int t = 0; t < steps; ++t) {
            const int cur = t & 1;
            const int base = n0 + t * ROWS;
            const bool morex = (t + 1 < steps);
            float4 xstage = make_float4(0.f, 0.f, 0.f, 0.f);
            if (morex) {   // issue next x chunk's load early (hides under compute)
                const int nr = min(base + ROWS + xr, N - 1);
                xstage = *(const float4*)&xbase[(size_t)nr * I + xc];
            }
#pragma unroll
            for (int g = 0; g < ROWS / 4; ++g) {
                // prefetch next 4 D rows (crosses into next step at g=3)
                float2 dn[4];
#pragma unroll
                for (int k = 0; k < 4; ++k) {
                    const int n1 = base + (g + 1) * 4 + k;
                    dn[k] = (n1 < nend) ? *(const float2*)&Dbase[(size_t)n1 * M] : z2;
                }
                // compute rows g*4 .. g*4+3 with previously-loaded D
#pragma unroll
                for (int k = 0; k < 4; ++k) {
                    const int r = g * 4 + k;
                    const float2 d2 = dc[k];
                    float xv[16];
                    *(float4*)&xv[0]  = *(const float4*)&ldsX[cur][r][i_base + 0];
                    *(float4*)&xv[4]  = *(const float4*)&ldsX[cur][r][i_base + 4];
                    *(float4*)&xv[8]  = *(const float4*)&ldsX[cur][r][i_base + 8];
                    *(float4*)&xv[12] = *(const float4*)&ldsX[cur][r][i_base + 12];
#pragma unroll
                    for (int cc = 0; cc < 16; ++cc) {
                        acc[0][cc] = fmaf(d2.x, xv[cc], acc[0][cc]);
                        acc[1][cc] = fmaf(d2.y, xv[cc], acc[1][cc]);
                    }
                }
#pragma unroll
                for (int k = 0; k < 4; ++k) dc[k] = dn[k];
            }
            __syncthreads();               // all reads of ldsX[cur] done
            if (morex)
                *(float4*)&ldsX[cur ^ 1][xr][xc] = xstage;
            __syncthreads();               // next buffer visible
        }
    }

    // store partial tile, coalesced: j = mh*8192 + (a*16+cc)*256 + tid
    float* p = partial + ((size_t)s * B + b) * MI + mh * (MH * I);
#pragma unroll
    for (int a = 0; a < 2; ++a)
#pragma unroll
        for (int cc = 0; cc < 16; ++cc)
            p[((a * 16 + cc) << 8) + tid] = acc[a][cc];
}

// ---------------- Reduce: dtx[b][m][i] = sum_s partial[s][b][j(m,i)]
__global__ __launch_bounds__(256) void reduce_partials(const float* __restrict__ partial,
                                                       float* __restrict__ dtx,
                                                       int nsplit) {
    const int bb = blockIdx.y;
    const int j = blockIdx.x * 256 + threadIdx.x;   // 0..MI-1
    const float* p = partial + (size_t)bb * MI + j;
    float sum = 0.f;
#pragma unroll 4
    for (int s = 0; s < nsplit; ++s)
        sum += p[(size_t)s * B * MI];
    // invert stage1 layout: j = mh*8192 + (a*16+cc)*256 + t
    const int mhh  = j >> 13;
    const int jj   = j & 8191;
    const int cidx = jj >> 8;     // 0..31 = a*16+cc
    const int t    = jj & 255;
    const int a  = cidx >> 4;
    const int cc = cidx & 15;
    const int m = mhh * MH + (t & 63) * 2 + a;
    const int i = (t >> 6) * 16 + cc;
    dtx[(size_t)bb * MI + m * I + i] = sum;
}

// ---------------- Stage 2: S[b][m][o] = (1/16) * sum_i coeff[o][i][m] * dtx[b][m][i]
__global__ __launch_bounds__(256) void stage2(const float* __restrict__ coeff,
                                              const float* __restrict__ dtx,
                                              float* __restrict__ S) {
    const int g = blockIdx.x * 256 + threadIdx.x;   // 0 .. B*O*M-1
    const int b = g >> 14;            // O*M = 16384
    const int rem = g & 16383;
    const int o = rem >> 8;
    const int m = rem & 255;
    const float* dt = dtx + (size_t)b * M * I + (size_t)m * I;
    const float* cf = coeff + (size_t)o * I * M + m;
    float acc = 0.f;
#pragma unroll 8
    for (int i = 0; i < I; ++i)
        acc = fmaf(cf[(size_t)i * M], dt[i], acc);
    S[(size_t)b * M * O + (size_t)m * O + o] = acc * 0.0625f;   // 1/sqrt(256)
}

// ---------------- Stage 3: out[b][n][o] = sum_m D[b][n][m] * S[b][m][o]
// NTILE=256, thread owns 4 n x 16 o (64 acc) -> 64 FMA per m-step.
#define MC 32
#define NT3 256
#define NBLK3 ((N + NT3 - 1) / NT3)   // 79

__global__ __launch_bounds__(256) void stage3(const float* __restrict__ Dg,
                                              const float* __restrict__ Sg,
                                              float* __restrict__ outg) {
    const int b = blockIdx.y;
    const int n0 = blockIdx.x * NT3;
    const int tid = threadIdx.x;
    const int nl = tid & 63;
    const int o_base = (tid >> 6) * 16;

    __shared__ float Dt[NT3][MC + 1];   // 33 KB, stride 33 -> 2-way max (free)
    __shared__ float St[MC][O];         // 8 KB

    float acc[4][16];
#pragma unroll
    for (int w = 0; w < 4; ++w)
#pragma unroll
        for (int j = 0; j < 16; ++j) acc[w][j] = 0.f;

    const float* Db = Dg + (size_t)b * N * M;
    const float* Sb = Sg + (size_t)b * M * O;

    for (int mc = 0; mc < M; mc += MC) {
#pragma unroll
        for (int rr = 0; rr < 8; ++rr) {
            const int f = tid + rr * 256;      // 0..2047 float4 slots
            const int n_row = f >> 3;          // 0..255
            const int m_off = (f & 7) * 4;     // 0..28
            const int gn = min(n0 + n_row, N - 1);
            float4 d4 = *(const float4*)&Db[(size_t)gn * M + mc + m_off];
            Dt[n_row][m_off + 0] = d4.x;
            Dt[n_row][m_off + 1] = d4.y;
            Dt[n_row][m_off + 2] = d4.z;
            Dt[n_row][m_off + 3] = d4.w;
            if (rr < 2) {   // S chunk: contiguous copy of 2048 floats
                *(float4*)((float*)St + (size_t)f * 4) =
                    *(const float4*)&Sb[(size_t)mc * O + (size_t)f * 4];
            }
        }
        __syncthreads();
#pragma unroll 4
        for (int mm = 0; mm < MC; ++mm) {
            float dv[4];
#pragma unroll
            for (int w = 0; w < 4; ++w) dv[w] = Dt[nl + 64 * w][mm];
            float sv[16];
            *(float4*)&sv[0]  = *(const float4*)&St[mm][o_base + 0];
            *(float4*)&sv[4]  = *(const float4*)&St[mm][o_base + 4];
            *(float4*)&sv[8]  = *(const float4*)&St[mm][o_base + 8];
            *(float4*)&sv[12] = *(const float4*)&St[mm][o_base + 12];
#pragma unroll
            for (int w = 0; w < 4; ++w)
#pragma unroll
                for (int j = 0; j < 16; ++j)
                    acc[w][j] = fmaf(dv[w], sv[j], acc[w][j]);
        }
        __syncthreads();
    }

#pragma unroll
    for (int w = 0; w < 4; ++w) {
        const int gn = n0 + nl + 64 * w;
        if (gn < N) {
            float* op = outg + ((size_t)b * N + gn) * O + o_base;
            *(float4*)&op[0]  = make_float4(acc[w][0],  acc[w][1],  acc[w][2],  acc[w][3]);
            *(float4*)&op[4]  = make_float4(acc[w][4],  acc[w][5],  acc[w][6],  acc[w][7]);
            *(float4*)&op[8]  = make_float4(acc[w][8],  acc[w][9],  acc[w][10], acc[w][11]);
            *(float4*)&op[12] = make_float4(acc[w][12], acc[w][13], acc[w][14], acc[w][15]);
        }
    }
}

extern "C" void kernel_launch(void* const* d_in, const int* in_sizes, int n_in,
                              void* d_out, int out_size, void* d_ws, size_t ws_size,
                              hipStream_t stream) {
    const float* Dg    = (const float*)d_in[0];
    const float* xg    = (const float*)d_in[1];
    const float* coeff = (const float*)d_in[2];
    float* outg = (float*)d_out;

    float* dtx     = (float*)d_ws;                   // B*MI floats = 512 KB
    float* S       = dtx + (size_t)B * MI;           // B*M*O floats = 512 KB
    float* partial = S + (size_t)B * M * O;          // split * B*MI floats

    // Choose split-K factor from available workspace (deterministic in ws_size).
    // Cap 64: grid 64*8*2 = 1024 blocks = one full residency pass at 4 blocks/CU.
    const size_t fixed = 2ull * B * MI * sizeof(float);
    const size_t per   = (size_t)B * MI * sizeof(float);   // 512 KB per slot
    int split = 1;
    if (ws_size > fixed) {
        size_t cap = (ws_size - fixed) / per;
        split = (int)(cap < 1 ? 1 : (cap > 64 ? 64 : cap));
    }
    int chunk = ((N + split - 1) / split + ROWS - 1) & ~(ROWS - 1);

    stage1<<<dim3(split, B, 2), 256, 0, stream>>>(Dg, xg, partial, chunk);
    reduce_partials<<<dim3(MI / 256, B), 256, 0, stream>>>(partial, dtx, split);
    stage2<<<dim3((B * O * M) / 256), 256, 0, stream>>>(coeff, dtx, S);
    stage3<<<dim3(NBLK3, B), 256, 0, stream>>>(Dg, S, outg);
}

// Round 10
// 152.886 us; speedup vs baseline: 11.9997x; 1.7825x over previous
//
#include <hip/hip_runtime.h>

#define B 8
#define N 20000
#define M 256
#define I 64
#define O 64
#define MI (M * I)          // 16384
#define KT 32               // n-rows per MFMA K-tile (stage1)
#define SDS 40              // LDS row stride (u16) for bf16 tiles: 80 B, 16B-aligned frags
#define SSS 264             // stage3 S^T LDS row stride (u16): 528 B = 33*16

typedef __attribute__((ext_vector_type(8))) short   bf16x8;   // 8 bf16 (4 VGPR)
typedef __attribute__((ext_vector_type(4))) float   f32x4;    // MFMA acc
typedef __attribute__((ext_vector_type(4))) unsigned int uint4v;

// RNE fp32 -> bf16 pair pack (lo in bits 0-15, hi in 16-31)
__device__ __forceinline__ unsigned pk2bf(float lo, float hi) {
    unsigned a = __float_as_uint(lo);
    unsigned b = __float_as_uint(hi);
    a = (a + 0x7fffu + ((a >> 16) & 1u)) >> 16;
    b = (b + 0x7fffu + ((b >> 16) & 1u)) >> 16;
    return a | (b << 16);
}

__device__ __forceinline__ unsigned short f2bf(float v) {
    unsigned a = __float_as_uint(v);
    return (unsigned short)((a + 0x7fffu + ((a >> 16) & 1u)) >> 16);
}

// ---------------- Stage 1 (MFMA): partial[s][b][m][i] = sum_n D[b,n,m]*x[b,n,i]
// Block = 256 thr = 4 waves; tile = full 256m x 64i, K-chunk of n.
// D,x are n-major (k non-contiguous) -> transpose during bf16 LDS staging with
// scalar pair-packed writes. Bank swizzle col = n ^ ((row&3)<<3) cancels on the
// b128 frag read (base k8 ^ g(row) yields n = k8..k8+7 in canonical order), so
// A and B keep a consistent k-map (any consistent k-permutation is exact).
// Wave w owns m in [w*64, w*64+64): 4 m-subtiles x 4 i-subtiles = 16 MFMA/step.
__global__ __launch_bounds__(256) void stage1(const float* __restrict__ Dg,
                                              const float* __restrict__ xg,
                                              float* __restrict__ partial,
                                              int chunk) {
    const int b = blockIdx.y, s = blockIdx.x;
    const int n0 = s * chunk;
    const int nend = min(n0 + chunk, N);
    const int tid = threadIdx.x;
    const int lane = tid & 63;
    const int w = tid >> 6;

    __shared__ unsigned short sD[256 * SDS];   // 20.0 KB
    __shared__ unsigned short sX[64 * SDS];    //  5.0 KB

    f32x4 acc[4][4];
#pragma unroll
    for (int a = 0; a < 4; ++a)
#pragma unroll
        for (int v = 0; v < 4; ++v) acc[a][v] = (f32x4){0.f, 0.f, 0.f, 0.f};

    const float* Db = Dg + (size_t)b * N * M;
    const float* xb = xg + (size_t)b * N * I;

    const int steps = (nend > n0) ? (nend - n0 + KT - 1) / KT : 0;

    for (int t = 0; t < steps; ++t) {
        const int nb = n0 + t * KT;
        // ---- D transpose-stage: thread owns global column m = tid
        {
            const float* dcol = Db + tid;              // lane-contiguous addresses
            const int gsh = (tid & 3) << 3;            // per n: 256 threads = 1KB coalesced
            unsigned short* drow = &sD[tid * SDS];
#pragma unroll
            for (int np = 0; np < 16; ++np) {
                const int n1 = nb + 2 * np;
                float lo = (n1 < nend)     ? dcol[(size_t)n1 * M]       : 0.f;
                float hi = (n1 + 1 < nend) ? dcol[(size_t)(n1 + 1) * M] : 0.f;
                *(unsigned*)&drow[(2 * np) ^ gsh] = pk2bf(lo, hi);
            }
        }
        // ---- x transpose-stage: thread owns i = tid&63, n-pairs {xq,+4,+8,+12}
        {
            const int xi = tid & 63, xq = tid >> 6;
            const float* xcol = xb + xi;
            const int gsh = (xi & 3) << 3;
            unsigned short* xrow = &sX[xi * SDS];
#pragma unroll
            for (int q = 0; q < 4; ++q) {
                const int np = xq + q * 4;
                const int n1 = nb + 2 * np;
                float lo = (n1 < nend)     ? xcol[(size_t)n1 * I]       : 0.f;
                float hi = (n1 + 1 < nend) ? xcol[(size_t)(n1 + 1) * I] : 0.f;
                *(unsigned*)&xrow[(2 * np) ^ gsh] = pk2bf(lo, hi);
            }
        }
        __syncthreads();
        // ---- fragments + MFMA
        const int k8 = (lane >> 4) << 3;
        bf16x8 bfr[4];
#pragma unroll
        for (int v = 0; v < 4; ++v) {
            const int i = v * 16 + (lane & 15);
            bfr[v] = *(const bf16x8*)&sX[i * SDS + (k8 ^ ((i & 3) << 3))];
        }
#pragma unroll
        for (int sm = 0; sm < 4; ++sm) {
            const int m = w * 64 + sm * 16 + (lane & 15);
            bf16x8 afr = *(const bf16x8*)&sD[m * SDS + (k8 ^ ((m & 3) << 3))];
#pragma unroll
            for (int v = 0; v < 4; ++v)
                acc[sm][v] = __builtin_amdgcn_mfma_f32_16x16x32_bf16(
                    afr, bfr[v], acc[sm][v], 0, 0, 0);
        }
        __syncthreads();
    }

    // ---- store partial tile in natural [m][i] layout
    // C-map (m89, HW-verified): col = lane&15 (i), row = (lane>>4)*4 + r (m)
    float* p = partial + ((size_t)s * B + b) * MI;
#pragma unroll
    for (int sm = 0; sm < 4; ++sm)
#pragma unroll
        for (int v = 0; v < 4; ++v)
#pragma unroll
            for (int r = 0; r < 4; ++r) {
                const int m = w * 64 + sm * 16 + ((lane >> 4) << 2) + r;
                const int i = v * 16 + (lane & 15);
                p[m * I + i] = acc[sm][v][r];
            }
}

// ---------------- Reduce: dtx[b][j] = sum_s partial[s][b][j]  (natural layout)
__global__ __launch_bounds__(256) void reduce_partials(const float* __restrict__ partial,
                                                       float* __restrict__ dtx,
                                                       int nsplit) {
    const int bb = blockIdx.y;
    const int j = blockIdx.x * 256 + threadIdx.x;
    const float* p = partial + (size_t)bb * MI + j;
    float sum = 0.f;
#pragma unroll 4
    for (int s = 0; s < nsplit; ++s)
        sum += p[(size_t)s * B * MI];
    dtx[(size_t)bb * MI + j] = sum;
}

// ---------------- Stage 2: ST[b][o][m] = bf16( (1/16) sum_i coeff[o][i][m]*dtx[b][m][i] )
// Emits S TRANSPOSED (o-major, m contiguous) so stage3 B-frags are k-contiguous.
__global__ __launch_bounds__(256) void stage2(const float* __restrict__ coeff,
                                              const float* __restrict__ dtx,
                                              unsigned short* __restrict__ ST) {
    const int g = blockIdx.x * 256 + threadIdx.x;
    const int b = g >> 14;            // O*M = 16384
    const int rem = g & 16383;
    const int o = rem >> 8;
    const int m = rem & 255;
    const float* dt = dtx + (size_t)b * MI + (size_t)m * I;
    const float* cf = coeff + (size_t)o * I * M + m;
    float acc = 0.f;
#pragma unroll 8
    for (int i = 0; i < I; ++i)
        acc = fmaf(cf[(size_t)i * M], dt[i], acc);
    ST[((size_t)b * O + o) * M + m] = f2bf(acc * 0.0625f);   // 1/sqrt(256)
}

// ---------------- Stage 3 (MFMA): out[b][n][o] = sum_m D[b,n,m] * S[b,m,o]
// A = D rows (k=m contiguous): per-lane global dwordx4 + inline bf16 cvt, no LDS.
// B = S^T staged once per block into LDS (padded stride). K = 256 = 8 steps.
// Block = 4 waves; wave w owns n in [n0 + w*64, +64): 16 MFMA per k-step.
__global__ __launch_bounds__(256) void stage3(const float* __restrict__ Dg,
                                              const unsigned short* __restrict__ STg,
                                              float* __restrict__ outg) {
    const int b = blockIdx.y;
    const int n0 = blockIdx.x * 256;
    const int tid = threadIdx.x;
    const int lane = tid & 63;
    const int w = tid >> 6;

    __shared__ unsigned short sS[64 * SSS];   // 33 KB

    // stage S^T tile (64 o x 256 m bf16): 4 threads per o-row, each copies its
    // 64-u16 segment as 8 x 16B stores. (Round-9 bug: stride c*16 u16 with a
    // 16B store covered only half the segment -> uninitialized LDS -> NaN.)
    {
        const int o = tid >> 2, seg = (tid & 3) * 64;
        const unsigned short* src = STg + ((size_t)b * O + o) * M + seg;
        unsigned short* dst = &sS[o * SSS + seg];
#pragma unroll
        for (int c = 0; c < 8; ++c)
            *(uint4v*)&dst[c * 8] = *(const uint4v*)&src[c * 8];
    }

    f32x4 acc[4][4];
#pragma unroll
    for (int a = 0; a < 4; ++a)
#pragma unroll
        for (int v = 0; v < 4; ++v) acc[a][v] = (f32x4){0.f, 0.f, 0.f, 0.f};

    __syncthreads();

    const float* Db = Dg + (size_t)b * N * M;
    const int k8 = (lane >> 4) << 3;

#pragma unroll 1
    for (int ks = 0; ks < 8; ++ks) {
        const int kb = ks * 32 + k8;
        bf16x8 bfr[4];
#pragma unroll
        for (int v = 0; v < 4; ++v)
            bfr[v] = *(const bf16x8*)&sS[(v * 16 + (lane & 15)) * SSS + kb];
#pragma unroll
        for (int sn = 0; sn < 4; ++sn) {
            int n = n0 + w * 64 + sn * 16 + (lane & 15);
            n = min(n, N - 1);                       // tail clamp (stores guarded)
            const float* ap = Db + (size_t)n * M + kb;
            const float4 f0 = *(const float4*)ap;
            const float4 f1 = *(const float4*)(ap + 4);
            uint4v pk = {pk2bf(f0.x, f0.y), pk2bf(f0.z, f0.w),
                         pk2bf(f1.x, f1.y), pk2bf(f1.z, f1.w)};
            bf16x8 afr = __builtin_bit_cast(bf16x8, pk);
#pragma unroll
            for (int v = 0; v < 4; ++v)
                acc[sn][v] = __builtin_amdgcn_mfma_f32_16x16x32_bf16(
                    afr, bfr[v], acc[sn][v], 0, 0, 0);
        }
    }

    // store: C-map col = lane&15 (o), row = (lane>>4)*4 + r (n)
#pragma unroll
    for (int sn = 0; sn < 4; ++sn)
#pragma unroll
        for (int v = 0; v < 4; ++v)
#pragma unroll
            for (int r = 0; r < 4; ++r) {
                const int n = n0 + w * 64 + sn * 16 + ((lane >> 4) << 2) + r;
                if (n < N)
                    outg[((size_t)b * N + n) * O + v * 16 + (lane & 15)] = acc[sn][v][r];
            }
}

extern "C" void kernel_launch(void* const* d_in, const int* in_sizes, int n_in,
                              void* d_out, int out_size, void* d_ws, size_t ws_size,
                              hipStream_t stream) {
    const float* Dg    = (const float*)d_in[0];
    const float* xg    = (const float*)d_in[1];
    const float* coeff = (const float*)d_in[2];
    float* outg = (float*)d_out;

    float* base = (float*)d_ws;
    float* dtx = base;                                   // B*MI floats   (512 KB)
    unsigned short* ST = (unsigned short*)(base + B * MI);  // B*O*M bf16 (256 KB)
    float* partial = base + B * MI + B * MI / 2;         // split * B*MI floats

    // split-K from workspace (deterministic in ws_size); cap 64 ->
    // grid 64*8 = 512 four-wave blocks = 2 blocks/CU (VGPR<=256 tolerant).
    const size_t fixed = (size_t)B * MI * 4 + (size_t)B * MI * 2;
    const size_t per   = (size_t)B * MI * sizeof(float);
    int split = 1;
    if (ws_size > fixed) {
        size_t cap = (ws_size - fixed) / per;
        split = (int)(cap < 1 ? 1 : (cap > 64 ? 64 : cap));
    }
    int chunk = ((N + split - 1) / split + KT - 1) & ~(KT - 1);

    stage1<<<dim3(split, B), 256, 0, stream>>>(Dg, xg, partial, chunk);
    reduce_partials<<<dim3(MI / 256, B), 256, 0, stream>>>(partial, dtx, split);
    stage2<<<dim3((B * O * M) / 256), 256, 0, stream>>>(coeff, dtx, ST);
    stage3<<<dim3((N + 255) / 256, B), 256, 0, stream>>>(Dg, ST, outg);
}

// Round 11
// 116.658 us; speedup vs baseline: 15.7262x; 1.3105x over previous
//
#include <hip/hip_runtime.h>

#define B 8
#define N 20000
#define M 256
#define I 64
#define O 64
#define MI (M * I)          // 16384
#define KT 32               // n-rows per MFMA K-tile (stage1)
#define SSS 264             // stage3 S^T LDS row stride (u16): 528 B = 33*16

typedef __attribute__((ext_vector_type(8))) short   bf16x8;   // 8 bf16 (4 VGPR)
typedef __attribute__((ext_vector_type(4))) float   f32x4;    // MFMA acc
typedef __attribute__((ext_vector_type(4))) unsigned int uint4v;

// RNE fp32 -> bf16 pair pack (lo in bits 0-15, hi in 16-31)
__device__ __forceinline__ unsigned pk2bf(float lo, float hi) {
    unsigned a = __float_as_uint(lo);
    unsigned b = __float_as_uint(hi);
    a = (a + 0x7fffu + ((a >> 16) & 1u)) >> 16;
    b = (b + 0x7fffu + ((b >> 16) & 1u)) >> 16;
    return a | (b << 16);
}

__device__ __forceinline__ unsigned short f2bf(float v) {
    unsigned a = __float_as_uint(v);
    return (unsigned short)((a + 0x7fffu + ((a >> 16) & 1u)) >> 16);
}

// ---------------- Stage 1 (MFMA): partial[s][b][m][i] = sum_n D[b,n,m]*x[b,n,i]
// Block = 256 thr = 4 waves; tile = full 256m x 64i, K-chunk of n.
// LDS layout = 16B cells [g][row][8]: cell (g,row) holds bf16 of n = nb+g*8+..+7
// for column `row`. Staging: thread packs 8 scalars -> ONE ds_write_b128/cell;
// consecutive lanes hit consecutive cells -> 2 lanes/bank = conflict-free
// (round-10 layout: 80B row stride -> 8-way conflicts, 9.76M conflict-cycles).
// Frag reads are likewise 16 consecutive 16B cells per 16-lane group. k-map is
// canonical (element j = n nb+g*8+j) for both A and B -> exact contraction.
__global__ __launch_bounds__(256) void stage1(const float* __restrict__ Dg,
                                              const float* __restrict__ xg,
                                              float* __restrict__ partial,
                                              int chunk) {
    const int b = blockIdx.y, s = blockIdx.x;
    const int n0 = s * chunk;
    const int nend = min(n0 + chunk, N);
    const int tid = threadIdx.x;
    const int lane = tid & 63;
    const int w = tid >> 6;

    __shared__ unsigned short sD[4 * 256 * 8];   // 16 KB: (g*256 + m)*8
    __shared__ unsigned short sX[4 * 64 * 8];    //  4 KB: (g*64  + i)*8

    f32x4 acc[4][4];
#pragma unroll
    for (int a = 0; a < 4; ++a)
#pragma unroll
        for (int v = 0; v < 4; ++v) acc[a][v] = (f32x4){0.f, 0.f, 0.f, 0.f};

    const float* Db = Dg + (size_t)b * N * M;
    const float* xb = xg + (size_t)b * N * I;

    const int steps = (nend > n0) ? (nend - n0 + KT - 1) / KT : 0;

    for (int t = 0; t < steps; ++t) {
        const int nb = n0 + t * KT;
        // ---- D transpose-stage: thread owns global column m = tid.
        // Loads coalesced per instruction (lane-contiguous addresses).
        {
            const float* dcol = Db + tid;
#pragma unroll
            for (int g = 0; g < 4; ++g) {
                uint4v cell;
#pragma unroll
                for (int ee = 0; ee < 4; ++ee) {
                    const int n1 = nb + g * 8 + 2 * ee;
                    float lo = (n1 < nend)     ? dcol[(size_t)n1 * M]       : 0.f;
                    float hi = (n1 + 1 < nend) ? dcol[(size_t)(n1 + 1) * M] : 0.f;
                    cell[ee] = pk2bf(lo, hi);
                }
                *(uint4v*)&sD[(g * 256 + tid) * 8] = cell;
            }
        }
        // ---- x transpose-stage: wave w stages octet g=w; lane owns i=lane.
        {
            const int xi = tid & 63, g = tid >> 6;
            const float* xcol = xb + xi;
            uint4v cell;
#pragma unroll
            for (int ee = 0; ee < 4; ++ee) {
                const int n1 = nb + g * 8 + 2 * ee;
                float lo = (n1 < nend)     ? xcol[(size_t)n1 * I]       : 0.f;
                float hi = (n1 + 1 < nend) ? xcol[(size_t)(n1 + 1) * I] : 0.f;
                cell[ee] = pk2bf(lo, hi);
            }
            *(uint4v*)&sX[(g * 64 + xi) * 8] = cell;
        }
        __syncthreads();
        // ---- fragments + MFMA: 16-lane group gk reads octet g=gk
        const int g = lane >> 4;
        bf16x8 bfr[4];
#pragma unroll
        for (int v = 0; v < 4; ++v)
            bfr[v] = *(const bf16x8*)&sX[(g * 64 + v * 16 + (lane & 15)) * 8];
#pragma unroll
        for (int sm = 0; sm < 4; ++sm) {
            bf16x8 afr = *(const bf16x8*)&sD[(g * 256 + w * 64 + sm * 16 + (lane & 15)) * 8];
#pragma unroll
            for (int v = 0; v < 4; ++v)
                acc[sm][v] = __builtin_amdgcn_mfma_f32_16x16x32_bf16(
                    afr, bfr[v], acc[sm][v], 0, 0, 0);
        }
        __syncthreads();
    }

    // ---- store partial tile in natural [m][i] layout
    // C-map (m89, HW-verified): col = lane&15 (i), row = (lane>>4)*4 + r (m)
    float* p = partial + ((size_t)s * B + b) * MI;
#pragma unroll
    for (int sm = 0; sm < 4; ++sm)
#pragma unroll
        for (int v = 0; v < 4; ++v)
#pragma unroll
            for (int r = 0; r < 4; ++r) {
                const int m = w * 64 + sm * 16 + ((lane >> 4) << 2) + r;
                const int i = v * 16 + (lane & 15);
                p[m * I + i] = acc[sm][v][r];
            }
}

// ---------------- Reduce: dtx[b][j] = sum_s partial[s][b][j]  (natural layout)
__global__ __launch_bounds__(256) void reduce_partials(const float* __restrict__ partial,
                                                       float* __restrict__ dtx,
                                                       int nsplit) {
    const int bb = blockIdx.y;
    const int j = blockIdx.x * 256 + threadIdx.x;
    const float* p = partial + (size_t)bb * MI + j;
    float sum = 0.f;
#pragma unroll 4
    for (int s = 0; s < nsplit; ++s)
        sum += p[(size_t)s * B * MI];
    dtx[(size_t)bb * MI + j] = sum;
}

// ---------------- Stage 2: ST[b][o][m] = bf16( (1/16) sum_i coeff[o][i][m]*dtx[b][m][i] )
// Emits S TRANSPOSED (o-major, m contiguous) so stage3 B-frags are k-contiguous.
__global__ __launch_bounds__(256) void stage2(const float* __restrict__ coeff,
                                              const float* __restrict__ dtx,
                                              unsigned short* __restrict__ ST) {
    const int g = blockIdx.x * 256 + threadIdx.x;
    const int b = g >> 14;            // O*M = 16384
    const int rem = g & 16383;
    const int o = rem >> 8;
    const int m = rem & 255;
    const float* dt = dtx + (size_t)b * MI + (size_t)m * I;
    const float* cf = coeff + (size_t)o * I * M + m;
    float acc = 0.f;
#pragma unroll 8
    for (int i = 0; i < I; ++i)
        acc = fmaf(cf[(size_t)i * M], dt[i], acc);
    ST[((size_t)b * O + o) * M + m] = f2bf(acc * 0.0625f);   // 1/sqrt(256)
}

// ---------------- Stage 3 (MFMA): out[b][n][o] = sum_m D[b,n,m] * S[b,m,o]
// A = D rows (k=m contiguous): per-lane global dwordx4 + inline bf16 cvt, no LDS.
// B = S^T staged once per block into LDS (padded stride). K = 256 = 8 steps.
// Block = 4 waves; wave w owns n in [n0 + w*64, +64): 16 MFMA per k-step.
__global__ __launch_bounds__(256) void stage3(const float* __restrict__ Dg,
                                              const unsigned short* __restrict__ STg,
                                              float* __restrict__ outg) {
    const int b = blockIdx.y;
    const int n0 = blockIdx.x * 256;
    const int tid = threadIdx.x;
    const int lane = tid & 63;
    const int w = tid >> 6;

    __shared__ unsigned short sS[64 * SSS];   // 33 KB

    // stage S^T tile (64 o x 256 m bf16): 4 threads per o-row, 8 x 16B each
    {
        const int o = tid >> 2, seg = (tid & 3) * 64;
        const unsigned short* src = STg + ((size_t)b * O + o) * M + seg;
        unsigned short* dst = &sS[o * SSS + seg];
#pragma unroll
        for (int c = 0; c < 8; ++c)
            *(uint4v*)&dst[c * 8] = *(const uint4v*)&src[c * 8];
    }

    f32x4 acc[4][4];
#pragma unroll
    for (int a = 0; a < 4; ++a)
#pragma unroll
        for (int v = 0; v < 4; ++v) acc[a][v] = (f32x4){0.f, 0.f, 0.f, 0.f};

    __syncthreads();

    const float* Db = Dg + (size_t)b * N * M;
    const int k8 = (lane >> 4) << 3;

#pragma unroll 1
    for (int ks = 0; ks < 8; ++ks) {
        const int kb = ks * 32 + k8;
        bf16x8 bfr[4];
#pragma unroll
        for (int v = 0; v < 4; ++v)
            bfr[v] = *(const bf16x8*)&sS[(v * 16 + (lane & 15)) * SSS + kb];
#pragma unroll
        for (int sn = 0; sn < 4; ++sn) {
            int n = n0 + w * 64 + sn * 16 + (lane & 15);
            n = min(n, N - 1);                       // tail clamp (stores guarded)
            const float* ap = Db + (size_t)n * M + kb;
            const float4 f0 = *(const float4*)ap;
            const float4 f1 = *(const float4*)(ap + 4);
            uint4v pk = {pk2bf(f0.x, f0.y), pk2bf(f0.z, f0.w),
                         pk2bf(f1.x, f1.y), pk2bf(f1.z, f1.w)};
            bf16x8 afr = __builtin_bit_cast(bf16x8, pk);
#pragma unroll
            for (int v = 0; v < 4; ++v)
                acc[sn][v] = __builtin_amdgcn_mfma_f32_16x16x32_bf16(
                    afr, bfr[v], acc[sn][v], 0, 0, 0);
        }
    }

    // store: C-map col = lane&15 (o), row = (lane>>4)*4 + r (n)
#pragma unroll
    for (int sn = 0; sn < 4; ++sn)
#pragma unroll
        for (int v = 0; v < 4; ++v)
#pragma unroll
            for (int r = 0; r < 4; ++r) {
                const int n = n0 + w * 64 + sn * 16 + ((lane >> 4) << 2) + r;
                if (n < N)
                    outg[((size_t)b * N + n) * O + v * 16 + (lane & 15)] = acc[sn][v][r];
            }
}

extern "C" void kernel_launch(void* const* d_in, const int* in_sizes, int n_in,
                              void* d_out, int out_size, void* d_ws, size_t ws_size,
                              hipStream_t stream) {
    const float* Dg    = (const float*)d_in[0];
    const float* xg    = (const float*)d_in[1];
    const float* coeff = (const float*)d_in[2];
    float* outg = (float*)d_out;

    float* base = (float*)d_ws;
    float* dtx = base;                                   // B*MI floats   (512 KB)
    unsigned short* ST = (unsigned short*)(base + B * MI);  // B*O*M bf16 (256 KB)
    float* partial = base + B * MI + B * MI / 2;         // split * B*MI floats

    // split-K from workspace (deterministic in ws_size); cap 128 ->
    // grid up to 128*8 = 1024 four-wave blocks = 4 blocks/CU.
    const size_t fixed = (size_t)B * MI * 4 + (size_t)B * MI * 2;
    const size_t per   = (size_t)B * MI * sizeof(float);
    int split = 1;
    if (ws_size > fixed) {
        size_t cap = (ws_size - fixed) / per;
        split = (int)(cap < 1 ? 1 : (cap > 128 ? 128 : cap));
    }
    int chunk = ((N + split - 1) / split + KT - 1) & ~(KT - 1);

    stage1<<<dim3(split, B), 256, 0, stream>>>(Dg, xg, partial, chunk);
    reduce_partials<<<dim3(MI / 256, B), 256, 0, stream>>>(partial, dtx, split);
    stage2<<<dim3((B * O * M) / 256), 256, 0, stream>>>(coeff, dtx, ST);
    stage3<<<dim3((N + 255) / 256, B), 256, 0, stream>>>(Dg, ST, outg);
}

// Round 12
// 101.390 us; speedup vs baseline: 18.0945x; 1.1506x over previous
//
#include <hip/hip_runtime.h>

#define B 8
#define N 20000
#define M 256
#define I 64
#define O 64
#define MI (M * I)          // 16384
#define KT 32               // n-rows per MFMA K-tile (stage1)
#define SSS 264             // stage3 S^T LDS row stride (u16): 528 B = 33*16
// D-cell swizzle: spreads the 4-cells-per-lane ds_write_b128 pattern over all
// 8 bank-quads (unswizzled: lane bank-stride 16 -> 32-way write conflict).
// Bijective within each 8-cell block; reads of 16 consecutive m stay a
// permutation of the same 16 cells -> both sides conflict-free.
#define MSW(m) ((m) ^ (((m) >> 3) & 7))

typedef __attribute__((ext_vector_type(8))) short   bf16x8;   // 8 bf16 (4 VGPR)
typedef __attribute__((ext_vector_type(4))) float   f32x4;    // MFMA acc
typedef __attribute__((ext_vector_type(4))) unsigned int uint4v;

// RNE fp32 -> bf16 pair pack (lo in bits 0-15, hi in 16-31)
__device__ __forceinline__ unsigned pk2bf(float lo, float hi) {
    unsigned a = __float_as_uint(lo);
    unsigned b = __float_as_uint(hi);
    a = (a + 0x7fffu + ((a >> 16) & 1u)) >> 16;
    b = (b + 0x7fffu + ((b >> 16) & 1u)) >> 16;
    return a | (b << 16);
}

__device__ __forceinline__ unsigned short f2bf(float v) {
    unsigned a = __float_as_uint(v);
    return (unsigned short)((a + 0x7fffu + ((a >> 16) & 1u)) >> 16);
}

// ---------------- Stage 1 (MFMA): partial[s][b][m][i] = sum_n D[b,n,m]*x[b,n,i]
// Round-11 limiter: 40 scalar dword loads/thread/step capped streaming at
// ~1 TB/s (per-instruction 256 B/wave bounds bytes-in-flight). Now: D staged
// via 8 x global_load_dwordx4 (1 KB/wave each) into registers -> register
// transpose -> 4 x ds_write_b128 (MSW-swizzled, conflict-free). Single barrier
// per step; next step's loads issued before the barrier, consumed after the
// MFMA phase -> load->use distance spans a full compute phase.
__global__ __launch_bounds__(256) void stage1(const float* __restrict__ Dg,
                                              const float* __restrict__ xg,
                                              float* __restrict__ partial,
                                              int chunk) {
    const int b = blockIdx.y, s = blockIdx.x;
    const int n0 = s * chunk;
    const int nend = min(n0 + chunk, N);
    const int tid = threadIdx.x;
    const int lane = tid & 63;
    const int w = tid >> 6;

    __shared__ unsigned short sD[2][4 * 256 * 8];   // 2 x 16 KB, cell (g,m)
    __shared__ unsigned short sX[2][4 * 64 * 8];    // 2 x  4 KB, cell (g,i)

    f32x4 acc[4][4];
#pragma unroll
    for (int a = 0; a < 4; ++a)
#pragma unroll
        for (int v = 0; v < 4; ++v) acc[a][v] = (f32x4){0.f, 0.f, 0.f, 0.f};

    const float* Db = Dg + (size_t)b * N * M;
    const float* xb = xg + (size_t)b * N * I;

    const int steps = (nend > n0) ? (nend - n0 + KT - 1) / KT : 0;

    float4 dreg[8];   // D rows nb+w*8+q, cols 4*lane..+3
    float  xreg[8];   // x rows nb+w*8+q, col lane

    if (steps > 0) {
        // prologue: issue step-0 loads (clamped addresses; masked at pack)
#pragma unroll
        for (int q = 0; q < 8; ++q) {
            const int nc = min(n0 + w * 8 + q, N - 1);
            dreg[q] = *(const float4*)&Db[(size_t)nc * M + lane * 4];
            xreg[q] = xb[(size_t)nc * I + lane];
        }

        for (int t = 0; t < steps; ++t) {
            const int nb = n0 + t * KT;
            const int cur = t & 1;
            // ---- mask tail rows to zero (in place)
#pragma unroll
            for (int q = 0; q < 8; ++q) {
                const bool valid = (nb + w * 8 + q) < nend;
                if (!valid) { dreg[q] = make_float4(0.f, 0.f, 0.f, 0.f); xreg[q] = 0.f; }
            }
            // ---- pack + LDS write (register transpose): 4 D cells + 1 x cell
#pragma unroll
            for (int j = 0; j < 4; ++j) {
                uint4v cell;
#pragma unroll
                for (int e = 0; e < 4; ++e)
                    cell[e] = pk2bf(((const float*)&dreg[2 * e])[j],
                                    ((const float*)&dreg[2 * e + 1])[j]);
                const int m = lane * 4 + j;
                *(uint4v*)&sD[cur][((size_t)w * 256 + MSW(m)) * 8] = cell;
            }
            {
                uint4v cell;
#pragma unroll
                for (int e = 0; e < 4; ++e)
                    cell[e] = pk2bf(xreg[2 * e], xreg[2 * e + 1]);
                *(uint4v*)&sX[cur][((size_t)w * 64 + lane) * 8] = cell;
            }
            // ---- issue next step's loads (hidden under barrier + MFMA phase)
            if (t + 1 < steps) {
                const int nb2 = nb + KT;
#pragma unroll
                for (int q = 0; q < 8; ++q) {
                    const int nc = min(nb2 + w * 8 + q, N - 1);
                    dreg[q] = *(const float4*)&Db[(size_t)nc * M + lane * 4];
                    xreg[q] = xb[(size_t)nc * I + lane];
                }
            }
            __syncthreads();   // buf[cur] writes visible (prev buf disjoint)
            // ---- fragments + MFMA: 16-lane group g reads octet g
            const int g = lane >> 4;
            bf16x8 bfr[4];
#pragma unroll
            for (int v = 0; v < 4; ++v)
                bfr[v] = *(const bf16x8*)&sX[cur][((size_t)g * 64 + v * 16 + (lane & 15)) * 8];
#pragma unroll
            for (int sm = 0; sm < 4; ++sm) {
                const int mm = w * 64 + sm * 16 + (lane & 15);
                bf16x8 afr = *(const bf16x8*)&sD[cur][((size_t)g * 256 + MSW(mm)) * 8];
#pragma unroll
                for (int v = 0; v < 4; ++v)
                    acc[sm][v] = __builtin_amdgcn_mfma_f32_16x16x32_bf16(
                        afr, bfr[v], acc[sm][v], 0, 0, 0);
            }
        }
    }

    // ---- store partial tile in natural [m][i] layout
    // C-map (m89, HW-verified): col = lane&15 (i), row = (lane>>4)*4 + r (m)
    float* p = partial + ((size_t)s * B + b) * MI;
#pragma unroll
    for (int sm = 0; sm < 4; ++sm)
#pragma unroll
        for (int v = 0; v < 4; ++v)
#pragma unroll
            for (int r = 0; r < 4; ++r) {
                const int m = w * 64 + sm * 16 + ((lane >> 4) << 2) + r;
                const int i = v * 16 + (lane & 15);
                p[m * I + i] = acc[sm][v][r];
            }
}

// ---------------- Reduce: dtx[b][j] = sum_s partial[s][b][j]  (natural layout)
__global__ __launch_bounds__(256) void reduce_partials(const float* __restrict__ partial,
                                                       float* __restrict__ dtx,
                                                       int nsplit) {
    const int bb = blockIdx.y;
    const int j = blockIdx.x * 256 + threadIdx.x;
    const float* p = partial + (size_t)bb * MI + j;
    float sum = 0.f;
#pragma unroll 4
    for (int s = 0; s < nsplit; ++s)
        sum += p[(size_t)s * B * MI];
    dtx[(size_t)bb * MI + j] = sum;
}

// ---------------- Stage 2: ST[b][o][m] = bf16( (1/16) sum_i coeff[o][i][m]*dtx[b][m][i] )
// Emits S TRANSPOSED (o-major, m contiguous) so stage3 B-frags are k-contiguous.
__global__ __launch_bounds__(256) void stage2(const float* __restrict__ coeff,
                                              const float* __restrict__ dtx,
                                              unsigned short* __restrict__ ST) {
    const int g = blockIdx.x * 256 + threadIdx.x;
    const int b = g >> 14;            // O*M = 16384
    const int rem = g & 16383;
    const int o = rem >> 8;
    const int m = rem & 255;
    const float* dt = dtx + (size_t)b * MI + (size_t)m * I;
    const float* cf = coeff + (size_t)o * I * M + m;
    float acc = 0.f;
#pragma unroll 8
    for (int i = 0; i < I; ++i)
        acc = fmaf(cf[(size_t)i * M], dt[i], acc);
    ST[((size_t)b * O + o) * M + m] = f2bf(acc * 0.0625f);   // 1/sqrt(256)
}

// ---------------- Stage 3 (MFMA): out[b][n][o] = sum_m D[b,n,m] * S[b,m,o]
// A = D rows (k=m contiguous): per-lane global dwordx4 + inline bf16 cvt, no LDS.
// B = S^T staged once per block into LDS (padded stride). K = 256 = 8 steps.
// Block = 4 waves; wave w owns n in [n0 + w*64, +64): 16 MFMA per k-step.
__global__ __launch_bounds__(256) void stage3(const float* __restrict__ Dg,
                                              const unsigned short* __restrict__ STg,
                                              float* __restrict__ outg) {
    const int b = blockIdx.y;
    const int n0 = blockIdx.x * 256;
    const int tid = threadIdx.x;
    const int lane = tid & 63;
    const int w = tid >> 6;

    __shared__ unsigned short sS[64 * SSS];   // 33 KB

    // stage S^T tile (64 o x 256 m bf16): 4 threads per o-row, 8 x 16B each
    {
        const int o = tid >> 2, seg = (tid & 3) * 64;
        const unsigned short* src = STg + ((size_t)b * O + o) * M + seg;
        unsigned short* dst = &sS[o * SSS + seg];
#pragma unroll
        for (int c = 0; c < 8; ++c)
            *(uint4v*)&dst[c * 8] = *(const uint4v*)&src[c * 8];
    }

    f32x4 acc[4][4];
#pragma unroll
    for (int a = 0; a < 4; ++a)
#pragma unroll
        for (int v = 0; v < 4; ++v) acc[a][v] = (f32x4){0.f, 0.f, 0.f, 0.f};

    __syncthreads();

    const float* Db = Dg + (size_t)b * N * M;
    const int k8 = (lane >> 4) << 3;

#pragma unroll 1
    for (int ks = 0; ks < 8; ++ks) {
        const int kb = ks * 32 + k8;
        bf16x8 bfr[4];
#pragma unroll
        for (int v = 0; v < 4; ++v)
            bfr[v] = *(const bf16x8*)&sS[(v * 16 + (lane & 15)) * SSS + kb];
#pragma unroll
        for (int sn = 0; sn < 4; ++sn) {
            int n = n0 + w * 64 + sn * 16 + (lane & 15);
            n = min(n, N - 1);                       // tail clamp (stores guarded)
            const float* ap = Db + (size_t)n * M + kb;
            const float4 f0 = *(const float4*)ap;
            const float4 f1 = *(const float4*)(ap + 4);
            uint4v pk = {pk2bf(f0.x, f0.y), pk2bf(f0.z, f0.w),
                         pk2bf(f1.x, f1.y), pk2bf(f1.z, f1.w)};
            bf16x8 afr = __builtin_bit_cast(bf16x8, pk);
#pragma unroll
            for (int v = 0; v < 4; ++v)
                acc[sn][v] = __builtin_amdgcn_mfma_f32_16x16x32_bf16(
                    afr, bfr[v], acc[sn][v], 0, 0, 0);
        }
    }

    // store: C-map col = lane&15 (o), row = (lane>>4)*4 + r (n)
#pragma unroll
    for (int sn = 0; sn < 4; ++sn)
#pragma unroll
        for (int v = 0; v < 4; ++v)
#pragma unroll
            for (int r = 0; r < 4; ++r) {
                const int n = n0 + w * 64 + sn * 16 + ((lane >> 4) << 2) + r;
                if (n < N)
                    outg[((size_t)b * N + n) * O + v * 16 + (lane & 15)] = acc[sn][v][r];
            }
}

extern "C" void kernel_launch(void* const* d_in, const int* in_sizes, int n_in,
                              void* d_out, int out_size, void* d_ws, size_t ws_size,
                              hipStream_t stream) {
    const float* Dg    = (const float*)d_in[0];
    const float* xg    = (const float*)d_in[1];
    const float* coeff = (const float*)d_in[2];
    float* outg = (float*)d_out;

    float* base = (float*)d_ws;
    float* dtx = base;                                   // B*MI floats   (512 KB)
    unsigned short* ST = (unsigned short*)(base + B * MI);  // B*O*M bf16 (256 KB)
    float* partial = base + B * MI + B * MI / 2;         // split * B*MI floats

    // split-K from workspace (deterministic in ws_size); cap 64 halves the
    // partial read/write traffic vs 128 (grid 512 four-wave blocks).
    const size_t fixed = (size_t)B * MI * 4 + (size_t)B * MI * 2;
    const size_t per   = (size_t)B * MI * sizeof(float);
    int split = 1;
    if (ws_size > fixed) {
        size_t cap = (ws_size - fixed) / per;
        split = (int)(cap < 1 ? 1 : (cap > 64 ? 64 : cap));
    }
    int chunk = ((N + split - 1) / split + KT - 1) & ~(KT - 1);

    stage1<<<dim3(split, B), 256, 0, stream>>>(Dg, xg, partial, chunk);
    reduce_partials<<<dim3(MI / 256, B), 256, 0, stream>>>(partial, dtx, split);
    stage2<<<dim3((B * O * M) / 256), 256, 0, stream>>>(coeff, dtx, ST);
    stage3<<<dim3((N + 255) / 256, B), 256, 0, stream>>>(Dg, ST, outg);
}